// Round 2
// baseline (387.340 us; speedup 1.0000x reference)
//
#include <hip/hip_runtime.h>
#include <math.h>

#define MU_PRIOR   0.6447f
#define LOGDET_SA  4.767705615349743f   /* 3*ln(4.9) */
#define INV_SA     (1.0f/4.9f)

#define CW      64              /* rows per wave-chunk (1 row/lane in compute) */
#define NF4C    144             /* CW*9/4 float4 per 9-wide array per chunk */
#define NF4R    80              /* CW*5/4 */
#define NF4M    48              /* CW*3/4 */
#define GRID    2048            /* persistent blocks (8/CU nominal) */

#define W0 (1.0f / (0.0015f  * 0.0015f))
#define W1 (1.0f / (0.0012f  * 0.0012f))
#define W2 (1.0f / (0.0010f  * 0.0010f))
#define W3 (1.0f / (0.00086f * 0.00086f))
#define W4 (1.0f / (0.00057f * 0.00057f))

__device__ __forceinline__ float warp_reduce_f(float v) {
#pragma unroll
    for (int off = 32; off > 0; off >>= 1) v += __shfl_down(v, off, 64);
    return v;
}

__device__ __forceinline__ double warp_reduce_d(double v) {
#pragma unroll
    for (int off = 32; off > 0; off >>= 1) v += __shfl_down(v, off, 64);
    return v;
}

// pack (pred-yobs)^2 with nan-flag in the sign bit (d2 >= 0 always)
__device__ __forceinline__ float comb1(float p, float y, float n) {
    const float d = p - y;
    const float d2 = d * d;
    const unsigned u = __float_as_uint(d2) | ((n == n) ? 0u : 0x80000000u);
    return __uint_as_float(u);
}
__device__ __forceinline__ float4 comb4(float4 p, float4 y, float4 n) {
    float4 o;
    o.x = comb1(p.x, y.x, n.x); o.y = comb1(p.y, y.y, n.y);
    o.z = comb1(p.z, y.z, n.z); o.w = comb1(p.w, y.w, n.w);
    return o;
}

// ONE chunk's in-flight registers. Exactly one instance is ever live
// (round-1 lesson: two instances -> 92-VGPR alloc + 57 MB scratch spill).
struct ChunkRegs {
    float4 p0, p1, p2, y0, y1, y2, n0, n1, n2, c0, c1, c2;
    float4 r0, q0, r1, q1, m0;
};

__device__ __forceinline__ void issue_loads(
    ChunkRegs& R, int c, int lane,
    const float* __restrict__ pred, const float* __restrict__ yobs,
    const float* __restrict__ rrs,  const float* __restrict__ rrsp,
    const float* __restrict__ nanarr, const float* __restrict__ cov,
    const float* __restrict__ mu)
{
    const float4* gP = reinterpret_cast<const float4*>(pred)   + (size_t)c * NF4C;
    const float4* gY = reinterpret_cast<const float4*>(yobs)   + (size_t)c * NF4C;
    const float4* gN = reinterpret_cast<const float4*>(nanarr) + (size_t)c * NF4C;
    const float4* gC = reinterpret_cast<const float4*>(cov)    + (size_t)c * NF4C;
    const float4* gR = reinterpret_cast<const float4*>(rrs)    + (size_t)c * NF4R;
    const float4* gQ = reinterpret_cast<const float4*>(rrsp)   + (size_t)c * NF4R;
    const float4* gM = reinterpret_cast<const float4*>(mu)     + (size_t)c * NF4M;

    R.p0 = gP[lane]; R.p1 = gP[lane + 64];
    R.y0 = gY[lane]; R.y1 = gY[lane + 64];
    R.n0 = gN[lane]; R.n1 = gN[lane + 64];
    R.c0 = gC[lane]; R.c1 = gC[lane + 64];
    R.r0 = gR[lane]; R.q0 = gQ[lane];
    if (lane < 16) {
        R.p2 = gP[lane + 128]; R.y2 = gY[lane + 128];
        R.n2 = gN[lane + 128]; R.c2 = gC[lane + 128];
        R.r1 = gR[lane + 64];  R.q1 = gQ[lane + 64];
    }
    if (lane < 48) R.m0 = gM[lane];
}

// Single fused kernel. Round-0 register structure (one ChunkRegs live, no
// spill) + rotating depth-1 prefetch: after chunk c's registers are consumed
// (reg terms + LDS pack), the SAME registers are re-loaded with chunk c+nw,
// and those loads stay in flight (counted vmcnt) under chunk c's LDS-read
// compute phase. NO __syncthreads in the loop: per-wave private LDS slices,
// same-wave ordering via lgkmcnt + wave_barrier. Final cross-block reduction
// is done by the last-finishing block (device-scope atomics; no 2nd launch).
__global__ __launch_bounds__(256) void loss_fused(
    const float* __restrict__ pred, const float* __restrict__ yobs,
    const float* __restrict__ rrs,  const float* __restrict__ rrsp,
    const float* __restrict__ nanarr, const float* __restrict__ cov,
    const float* __restrict__ mu, const float* __restrict__ params,
    double* __restrict__ partial, unsigned* __restrict__ counter,
    int nchunks, int rows, int nparams, float* __restrict__ out)
{
    __shared__ float4 sV[4 * NF4C];   // packed d2|nanflag, per-wave slices
    __shared__ float4 sC[4 * NF4C];   // cov, per-wave slices
    __shared__ float  smem[4];
    __shared__ double smd[4];
    __shared__ int    amLast;

    const int tid   = threadIdx.x;
    const int lane  = tid & 63;
    const int wid   = tid >> 6;
    const int wslot = wid * NF4C;
    const int wgid  = blockIdx.x * 4 + wid;
    const int nw    = (int)gridDim.x * 4;

    // per-lane rotated rrs weights: ew[k] = W[(4*lane + k) % 5]
    const int w0 = (5 - (lane % 5)) % 5;
    float ew[5];
#pragma unroll
    for (int k = 0; k < 5; ++k) {
        int idx = w0 + k; if (idx >= 5) idx -= 5;
        ew[k] = (idx == 0) ? W0 : (idx == 1) ? W1 : (idx == 2) ? W2
               : (idx == 3) ? W3 : W4;
    }

    float acc = 0.0f;
    ChunkRegs R;
    if (wgid < nchunks)
        issue_loads(R, wgid, lane, pred, yobs, rrs, rrsp, nanarr, cov, mu);

    for (int c = wgid; c < nchunks; c += nw) {
        // ---- rrs term from registers (chunk base ≡ 0 mod 5; i=lane+64
        //      rotates cols by +1 since 256 ≡ 1 mod 5) ----
        {
            float ra = 0.f;
            const float d0 = R.r0.x - R.q0.x, d1 = R.r0.y - R.q0.y;
            const float d2 = R.r0.z - R.q0.z, d3 = R.r0.w - R.q0.w;
            ra += d0 * d0 * ew[0] + d1 * d1 * ew[1]
                + d2 * d2 * ew[2] + d3 * d3 * ew[3];
            if (lane < 16) {
                const float e0 = R.r1.x - R.q1.x, e1 = R.r1.y - R.q1.y;
                const float e2 = R.r1.z - R.q1.z, e3 = R.r1.w - R.q1.w;
                ra += e0 * e0 * ew[1] + e1 * e1 * ew[2]
                    + e2 * e2 * ew[3] + e3 * e3 * ew[4];
            }
            acc += ra * 0.2f;
        }

        // ---- mu term from registers ----
        if (lane < 48) {
            const float d0 = R.m0.x - MU_PRIOR, d1 = R.m0.y - MU_PRIOR;
            const float d2 = R.m0.z - MU_PRIOR, d3 = R.m0.w - MU_PRIOR;
            acc += (d0 * d0 + d1 * d1 + d2 * d2 + d3 * d3) * (1.0f / 29.4f);
        }

        // ---- stage packed V and C into this wave's private LDS slice ----
        sV[wslot + lane]       = comb4(R.p0, R.y0, R.n0);
        sV[wslot + lane + 64]  = comb4(R.p1, R.y1, R.n1);
        sC[wslot + lane]       = R.c0;
        sC[wslot + lane + 64]  = R.c1;
        if (lane < 16) {
            sV[wslot + lane + 128] = comb4(R.p2, R.y2, R.n2);
            sC[wslot + lane + 128] = R.c2;
        }

        __builtin_amdgcn_wave_barrier();   // pin order; lgkmcnt handles data

        // ---- R is dead: re-issue the SAME registers for chunk c+nw.
        //      These loads stay outstanding across the LDS compute below
        //      (first use = pack at next loop top -> counted vmcnt there).
        if (c + nw < nchunks)
            issue_loads(R, c + nw, lane, pred, yobs, rrs, rrsp, nanarr, cov, mu);

        // ---- per-row terms: row = lane (9-float stride -> 2-way bank, free)
        {
            const float* v = reinterpret_cast<const float*>(sV + wslot) + 9 * lane;
            const float* m = reinterpret_cast<const float*>(sC + wslot) + 9 * lane;
            float dy2 = 0.f, len = 0.f;
#pragma unroll
            for (int k = 0; k < 9; ++k) {
                const unsigned u = __float_as_uint(v[k]);
                dy2 += __uint_as_float(u & 0x7fffffffu);
                len += (float)(1u - (u >> 31));
            }
            acc += 10.0f * dy2 / len;

            const float tr  = m[0] + m[4] + m[8];
            const float det = m[0] * (m[4] * m[8] - m[5] * m[7])
                            - m[1] * (m[3] * m[8] - m[5] * m[6])
                            + m[2] * (m[3] * m[7] - m[4] * m[6]);
            acc += 0.5f * (LOGDET_SA - __logf(det) + tr * INV_SA);
        }

        __builtin_amdgcn_wave_barrier();   // slice reuse next iter: keep order
    }

    // ---- block reduction -> double partial ----
    acc = warp_reduce_f(acc);
    if (lane == 0) smem[wid] = acc;
    __syncthreads();
    if (tid == 0) {
        const double bsum = (double)(smem[0] + smem[1] + smem[2] + smem[3]);
        __hip_atomic_store(&partial[blockIdx.x], bsum,
                           __ATOMIC_RELEASE, __HIP_MEMORY_SCOPE_AGENT);
        const unsigned prev = __hip_atomic_fetch_add(
            counter, 1u, __ATOMIC_ACQ_REL, __HIP_MEMORY_SCOPE_AGENT);
        amLast = (prev == (unsigned)gridDim.x - 1u);
    }
    __syncthreads();                 // amLast is block-uniform after this
    if (!amLast) return;

    // ---- last block: final reduction (replaces the old loss_final) ----
    double accA = 0.0;   // per-row total (un-normalized)
    double accB = 0.0;   // l2 over parameters (un-normalized)

    for (int i = tid; i < (int)gridDim.x; i += 256)
        accA += __hip_atomic_load(&partial[i],
                                  __ATOMIC_RELAXED, __HIP_MEMORY_SCOPE_AGENT);
    for (int i = tid; i < nparams; i += 256) {
        const float d = params[i] - 1.0f;
        accB += (double)(d * d);
    }

    // tail rows (rows % CW), scalar loads (zero iterations for N=1e6)
    const int mainRows = nchunks * CW;
    for (int r = mainRows + tid; r < rows; r += 256) {
        float dy2 = 0.f, len = 0.f;
        for (int i = 0; i < 9; ++i) {
            const float d = pred[9 * (size_t)r + i] - yobs[9 * (size_t)r + i];
            dy2 += d * d;
            const float v = nanarr[9 * (size_t)r + i];
            len += (v == v) ? 1.f : 0.f;
        }
        const float W[5] = {W0, W1, W2, W3, W4};
        float racc = 0.f;
        for (int i = 0; i < 5; ++i) {
            const float d = rrs[5 * (size_t)r + i] - rrsp[5 * (size_t)r + i];
            racc += d * d * W[i];
        }
        const float* m = cov + 9 * (size_t)r;
        const float tr  = m[0] + m[4] + m[8];
        const float det = m[0] * (m[4] * m[8] - m[5] * m[7])
                        - m[1] * (m[3] * m[8] - m[5] * m[6])
                        + m[2] * (m[3] * m[7] - m[4] * m[6]);
        float dm = 0.f;
        for (int i = 0; i < 3; ++i) {
            const float d = mu[3 * (size_t)r + i] - MU_PRIOR;
            dm += d * d;
        }
        accA += (double)(racc * 0.2f + 10.f * dy2 / len
                         + 0.5f * (LOGDET_SA - __logf(det) + tr * INV_SA)
                         + dm * (1.f / 29.4f));
    }

    double val = accA * (1.0 / (double)rows) + accB * (1.0 / (double)nparams);
    val = warp_reduce_d(val);
    if (lane == 0) smd[wid] = val;
    __syncthreads();
    if (tid == 0)
        out[0] = (float)(smd[0] + smd[1] + smd[2] + smd[3]);
}

extern "C" void kernel_launch(void* const* d_in, const int* in_sizes, int n_in,
                              void* d_out, int out_size, void* d_ws, size_t ws_size,
                              hipStream_t stream) {
    const float* pred   = (const float*)d_in[0];
    const float* yobs   = (const float*)d_in[1];
    const float* rrs    = (const float*)d_in[2];
    const float* rrsp   = (const float*)d_in[3];
    const float* nanarr = (const float*)d_in[4];
    const float* cov    = (const float*)d_in[5];
    const float* mu     = (const float*)d_in[6];
    const float* params = (const float*)d_in[7];
    float* out = (float*)d_out;

    const int rows    = in_sizes[0] / 9;
    const int nchunks = rows / CW;            // 15,625 for N=1e6 (exact)

    // 1 chunk per wave per sweep (round-0 geometry)
    int grid = (nchunks + 3) / 4;
    if (grid < 1) grid = 1;
    if (grid > GRID) grid = GRID;

    double*   partial = (double*)d_ws;                                  // grid doubles
    unsigned* counter = (unsigned*)((char*)d_ws + (size_t)GRID * sizeof(double));

    hipMemsetAsync(counter, 0, sizeof(unsigned), stream);  // graph-capturable
    loss_fused<<<grid, 256, 0, stream>>>(pred, yobs, rrs, rrsp, nanarr,
                                         cov, mu, params, partial, counter,
                                         nchunks, rows, in_sizes[7], out);
}

// Round 3
// 206.609 us; speedup vs baseline: 1.8748x; 1.8748x over previous
//
#include <hip/hip_runtime.h>
#include <math.h>

#define MU_PRIOR   0.6447f
#define LOGDET_SA  4.767705615349743f   /* 3*ln(4.9) */
#define INV_SA     (1.0f/4.9f)

#define CW      64              /* rows per wave-chunk (1 row/lane in compute) */
#define NF4C    144             /* CW*9/4 float4 per 9-wide array per chunk */
#define NF4R    80              /* CW*5/4 */
#define NF4M    48              /* CW*3/4 */
#define GRID    512             /* 2 blocks/CU (LDS dbuf = 73.7 KB/block) */

/* per-wave LDS buffer layout (bytes) */
#define BUF_P   0
#define BUF_Y   2304
#define BUF_N   4608
#define BUF_C   6912
#define BUFSZ   9216

#define W0 (1.0f / (0.0015f  * 0.0015f))
#define W1 (1.0f / (0.0012f  * 0.0012f))
#define W2 (1.0f / (0.0010f  * 0.0010f))
#define W3 (1.0f / (0.00086f * 0.00086f))
#define W4 (1.0f / (0.00057f * 0.00057f))

__device__ __forceinline__ float warp_reduce_f(float v) {
#pragma unroll
    for (int off = 32; off > 0; off >>= 1) v += __shfl_down(v, off, 64);
    return v;
}

__device__ __forceinline__ double warp_reduce_d(double v) {
#pragma unroll
    for (int off = 32; off > 0; off >>= 1) v += __shfl_down(v, off, 64);
    return v;
}

/* async 16B/lane global->LDS (no VGPR data path, counts 1 vmcnt) */
__device__ __forceinline__ void gld16(const void* g, void* l) {
    __builtin_amdgcn_global_load_lds(g, l, 16, 0, 0);
}

/* stage one chunk's p/y/n/cov (9216 B) into a wave-private LDS buffer.
 * 12 async instrs; LDS dest is wave-uniform base + lane*16 (linear layout,
 * matches natural row-major [64][9]). */
__device__ __forceinline__ void stage_chunk(
    char* lb, int c, int lane,
    const float* __restrict__ pred, const float* __restrict__ yobs,
    const float* __restrict__ nanarr, const float* __restrict__ cov)
{
    const float4* gP = reinterpret_cast<const float4*>(pred)   + (size_t)c * NF4C + lane;
    const float4* gY = reinterpret_cast<const float4*>(yobs)   + (size_t)c * NF4C + lane;
    const float4* gN = reinterpret_cast<const float4*>(nanarr) + (size_t)c * NF4C + lane;
    const float4* gC = reinterpret_cast<const float4*>(cov)    + (size_t)c * NF4C + lane;
    gld16(gP,      lb + BUF_P);
    gld16(gP + 64, lb + BUF_P + 1024);
    gld16(gY,      lb + BUF_Y);
    gld16(gY + 64, lb + BUF_Y + 1024);
    gld16(gN,      lb + BUF_N);
    gld16(gN + 64, lb + BUF_N + 1024);
    gld16(gC,      lb + BUF_C);
    gld16(gC + 64, lb + BUF_C + 1024);
    if (lane < 16) {
        gld16(gP + 128, lb + BUF_P + 2048);
        gld16(gY + 128, lb + BUF_Y + 2048);
        gld16(gN + 128, lb + BUF_N + 2048);
        gld16(gC + 128, lb + BUF_C + 2048);
    }
}

/* consume one chunk: LDS per-row terms (staged last iteration) + register
 * r/q/mu terms (loads issued at top, consumed after the LDS phase). */
__device__ __forceinline__ float body(
    const char* lb, int c, int lane, const float ew[5],
    const float* __restrict__ rrs, const float* __restrict__ rrsp,
    const float* __restrict__ mu)
{
    const float4* gR = reinterpret_cast<const float4*>(rrs)  + (size_t)c * NF4R;
    const float4* gQ = reinterpret_cast<const float4*>(rrsp) + (size_t)c * NF4R;
    const float4* gM = reinterpret_cast<const float4*>(mu)   + (size_t)c * NF4M;
    const float4 r0 = gR[lane], q0 = gQ[lane];
    float4 r1, q1, m0;
    if (lane < 16) { r1 = gR[lane + 64]; q1 = gQ[lane + 64]; }
    if (lane < 48) m0 = gM[lane];

    float acc = 0.0f;

    /* ---- per-row terms from LDS: row = lane, stride 9 floats (9 odd ->
     *      64 lanes land 2/bank = conflict-free) ---- */
    {
        const float* P = reinterpret_cast<const float*>(lb + BUF_P) + 9 * lane;
        const float* Y = reinterpret_cast<const float*>(lb + BUF_Y) + 9 * lane;
        const float* A = reinterpret_cast<const float*>(lb + BUF_N) + 9 * lane;
        const float* M = reinterpret_cast<const float*>(lb + BUF_C) + 9 * lane;
        float dy2 = 0.f, len = 0.f;
#pragma unroll
        for (int k = 0; k < 9; ++k) {
            const float d = P[k] - Y[k];
            dy2 += d * d;
            const float nv = A[k];
            len += (nv == nv) ? 1.f : 0.f;
        }
        acc += 10.0f * dy2 / len;

        const float tr  = M[0] + M[4] + M[8];
        const float det = M[0] * (M[4] * M[8] - M[5] * M[7])
                        - M[1] * (M[3] * M[8] - M[5] * M[6])
                        + M[2] * (M[3] * M[7] - M[4] * M[6]);
        acc += 0.5f * (LOGDET_SA - __logf(det) + tr * INV_SA);
    }

    /* ---- rrs term from registers (chunk base ≡ 0 mod 5; i=lane+64
     *      rotates cols by +1 since 256 ≡ 1 mod 5) ---- */
    {
        float ra = 0.f;
        const float d0 = r0.x - q0.x, d1 = r0.y - q0.y;
        const float d2 = r0.z - q0.z, d3 = r0.w - q0.w;
        ra += d0 * d0 * ew[0] + d1 * d1 * ew[1]
            + d2 * d2 * ew[2] + d3 * d3 * ew[3];
        if (lane < 16) {
            const float e0 = r1.x - q1.x, e1 = r1.y - q1.y;
            const float e2 = r1.z - q1.z, e3 = r1.w - q1.w;
            ra += e0 * e0 * ew[1] + e1 * e1 * ew[2]
                + e2 * e2 * ew[3] + e3 * e3 * ew[4];
        }
        acc += ra * 0.2f;
    }

    /* ---- mu term from registers ---- */
    if (lane < 48) {
        const float d0 = m0.x - MU_PRIOR, d1 = m0.y - MU_PRIOR;
        const float d2 = m0.z - MU_PRIOR, d3 = m0.w - MU_PRIOR;
        acc += (d0 * d0 + d1 * d1 + d2 * d2 + d3 * d3) * (1.0f / 29.4f);
    }
    return acc;
}

/* Two-kernel structure (round-0 proven; agent-scope atomics removed — on
 * gfx950 they cost a per-block L2 writeback+invalidate, +180 µs).
 * Pipeline: per wave, chunk c+nw is async-staged into the OTHER LDS buffer
 * (global_load_lds: no VGPRs, no spill) while chunk c is consumed. sA/sB are
 * distinct __shared__ objects + unroll-by-2, so the waitcnt pass can emit
 * counted vmcnt instead of a drain. No __syncthreads in the loop. */
__global__ __launch_bounds__(256) void loss_main(
    const float* __restrict__ pred, const float* __restrict__ yobs,
    const float* __restrict__ rrs,  const float* __restrict__ rrsp,
    const float* __restrict__ nanarr, const float* __restrict__ cov,
    const float* __restrict__ mu, double* __restrict__ partial, int nchunks)
{
    __shared__ __align__(16) char sA[4][BUFSZ];
    __shared__ __align__(16) char sB[4][BUFSZ];
    __shared__ float smem[4];

    const int tid  = threadIdx.x;
    const int lane = tid & 63;
    const int wid  = tid >> 6;
    const int wgid = blockIdx.x * 4 + wid;
    const int nw   = (int)gridDim.x * 4;

    char* bufA = sA[wid];
    char* bufB = sB[wid];

    /* per-lane rotated rrs weights: ew[k] = W[(4*lane + k) % 5] */
    const int w0 = (5 - (lane % 5)) % 5;
    float ew[5];
#pragma unroll
    for (int k = 0; k < 5; ++k) {
        int idx = w0 + k; if (idx >= 5) idx -= 5;
        ew[k] = (idx == 0) ? W0 : (idx == 1) ? W1 : (idx == 2) ? W2
               : (idx == 3) ? W3 : W4;
    }

    float acc = 0.0f;

    if (wgid < nchunks)
        stage_chunk(bufA, wgid, lane, pred, yobs, nanarr, cov);

    int c = wgid;
    while (c < nchunks) {
        /* --- consume A, prefetch into B --- */
        if (c + nw < nchunks)
            stage_chunk(bufB, c + nw, lane, pred, yobs, nanarr, cov);
        acc += body(bufA, c, lane, ew, rrs, rrsp, mu);
        c += nw;
        if (c >= nchunks) break;

        /* --- consume B, prefetch into A --- */
        if (c + nw < nchunks)
            stage_chunk(bufA, c + nw, lane, pred, yobs, nanarr, cov);
        acc += body(bufB, c, lane, ew, rrs, rrsp, mu);
        c += nw;
    }

    /* ---- block reduction -> double partial (plain store, no atomics) ---- */
    acc = warp_reduce_f(acc);
    if (lane == 0) smem[wid] = acc;
    __syncthreads();
    if (tid == 0)
        partial[blockIdx.x] = (double)(smem[0] + smem[1] + smem[2] + smem[3]);
}

__global__ __launch_bounds__(256) void loss_final(
    const double* __restrict__ partial, int npartials,
    const float* __restrict__ params, int nparams,
    const float* __restrict__ pred, const float* __restrict__ yobs,
    const float* __restrict__ rrs,  const float* __restrict__ rrsp,
    const float* __restrict__ nanarr, const float* __restrict__ cov,
    const float* __restrict__ mu, int mainRows, int rows,
    float* __restrict__ out)
{
    double accA = 0.0;   // per-row total (un-normalized)
    double accB = 0.0;   // l2 over parameters (un-normalized)

    for (int i = threadIdx.x; i < npartials; i += 256) accA += partial[i];
    for (int i = threadIdx.x; i < nparams; i += 256) {
        const float d = params[i] - 1.0f;
        accB += (double)(d * d);
    }

    // tail rows (rows % CW), scalar loads (zero iterations for N=1e6)
    for (int r = mainRows + (int)threadIdx.x; r < rows; r += 256) {
        float dy2 = 0.f, len = 0.f;
        for (int i = 0; i < 9; ++i) {
            const float d = pred[9 * (size_t)r + i] - yobs[9 * (size_t)r + i];
            dy2 += d * d;
            const float v = nanarr[9 * (size_t)r + i];
            len += (v == v) ? 1.f : 0.f;
        }
        const float W[5] = {W0, W1, W2, W3, W4};
        float racc = 0.f;
        for (int i = 0; i < 5; ++i) {
            const float d = rrs[5 * (size_t)r + i] - rrsp[5 * (size_t)r + i];
            racc += d * d * W[i];
        }
        const float* m = cov + 9 * (size_t)r;
        const float tr  = m[0] + m[4] + m[8];
        const float det = m[0] * (m[4] * m[8] - m[5] * m[7])
                        - m[1] * (m[3] * m[8] - m[5] * m[6])
                        + m[2] * (m[3] * m[7] - m[4] * m[6]);
        float dm = 0.f;
        for (int i = 0; i < 3; ++i) {
            const float d = mu[3 * (size_t)r + i] - MU_PRIOR;
            dm += d * d;
        }
        accA += (double)(racc * 0.2f + 10.f * dy2 / len
                         + 0.5f * (LOGDET_SA - __logf(det) + tr * INV_SA)
                         + dm * (1.f / 29.4f));
    }

    double val = accA * (1.0 / (double)rows) + accB * (1.0 / (double)nparams);
    val = warp_reduce_d(val);
    __shared__ double sm[4];
    const int lane = threadIdx.x & 63;
    const int wid  = threadIdx.x >> 6;
    if (lane == 0) sm[wid] = val;
    __syncthreads();
    if (threadIdx.x == 0)
        out[0] = (float)(sm[0] + sm[1] + sm[2] + sm[3]);
}

extern "C" void kernel_launch(void* const* d_in, const int* in_sizes, int n_in,
                              void* d_out, int out_size, void* d_ws, size_t ws_size,
                              hipStream_t stream) {
    const float* pred   = (const float*)d_in[0];
    const float* yobs   = (const float*)d_in[1];
    const float* rrs    = (const float*)d_in[2];
    const float* rrsp   = (const float*)d_in[3];
    const float* nanarr = (const float*)d_in[4];
    const float* cov    = (const float*)d_in[5];
    const float* mu     = (const float*)d_in[6];
    const float* params = (const float*)d_in[7];
    float* out = (float*)d_out;

    const int rows     = in_sizes[0] / 9;
    const int nchunks  = rows / CW;          // 15,625 for N=1e6 (exact)
    const int mainRows = nchunks * CW;
    int grid = (nchunks + 3) / 4;
    if (grid < 1) grid = 1;
    if (grid > GRID) grid = GRID;

    double* partial = (double*)d_ws;   // `grid` doubles, all written every call

    loss_main<<<grid, 256, 0, stream>>>(pred, yobs, rrs, rrsp, nanarr,
                                        cov, mu, partial, nchunks);
    loss_final<<<1, 256, 0, stream>>>(partial, grid, params, in_sizes[7],
                                      pred, yobs, rrs, rrsp, nanarr, cov, mu,
                                      mainRows, rows, out);
}